// Round 1
// baseline (638.353 us; speedup 1.0000x reference)
//
#include <hip/hip_runtime.h>
#include <hip/hip_bf16.h>
#include <cstdint>

#define N_NODES 100000
#define N_EDGES 1600000
#define DD 128

typedef float f32x4 __attribute__((ext_vector_type(4)));
typedef __bf16 bf16x8 __attribute__((ext_vector_type(8)));

union ABFrag { uint4 u4; uint16_t us[8]; bf16x8 v; };

__device__ __forceinline__ float bf2f(uint16_t u) {
  return __uint_as_float(((uint32_t)u) << 16);
}
__device__ __forceinline__ uint16_t f2bf(float f) {
  uint32_t u = __float_as_uint(f);
  uint32_t r = (u + 0x7fffu + ((u >> 16) & 1u)) >> 16;
  return (uint16_t)r;
}

// ---------------- CSR build ----------------
__global__ __launch_bounds__(256) void hist_k(const int* __restrict__ dst, int* __restrict__ deg) {
  int stride = gridDim.x * blockDim.x;
  for (int e = blockIdx.x * blockDim.x + threadIdx.x; e < N_EDGES; e += stride)
    atomicAdd(&deg[dst[e]], 1);
}

// single-block scan: cursor(=deg in) -> cursor(=exclusive out), row_ptr(=inclusive, shifted)
__global__ __launch_bounds__(1024) void scan_k(int* __restrict__ cursor, int* __restrict__ row_ptr) {
  __shared__ int wtot[16];
  __shared__ int wexc[17];
  __shared__ int sh_carry;
  const int tid = threadIdx.x, wv = tid >> 6, ln = tid & 63;
  if (tid == 0) { sh_carry = 0; row_ptr[0] = 0; }
  __syncthreads();
  for (int base = 0; base < N_NODES; base += 4096) {
    const int v = base + tid * 4;
    int4 d = make_int4(0, 0, 0, 0);
    if (v < N_NODES) d = *(const int4*)(cursor + v);
    const int s = d.x + d.y + d.z + d.w;
    int incl = s;
    #pragma unroll
    for (int o = 1; o < 64; o <<= 1) {
      int t = __shfl_up(incl, o);
      if (ln >= o) incl += t;
    }
    if (ln == 63) wtot[wv] = incl;
    __syncthreads();
    if (tid == 0) {
      int run = 0;
      #pragma unroll
      for (int i = 0; i < 16; ++i) { wexc[i] = run; run += wtot[i]; }
      wexc[16] = run;
    }
    __syncthreads();
    const int carry = sh_carry;
    if (v < N_NODES) {
      int p = carry + wexc[wv] + (incl - s);
      int e0 = p, e1 = e0 + d.x, e2 = e1 + d.y, e3 = e2 + d.z, e4 = e3 + d.w;
      *(int4*)(cursor + v) = make_int4(e0, e1, e2, e3);
      row_ptr[v + 1] = e1; row_ptr[v + 2] = e2; row_ptr[v + 3] = e3; row_ptr[v + 4] = e4;
    }
    __syncthreads();
    if (tid == 0) sh_carry = carry + wexc[16];
  }
}

__global__ __launch_bounds__(256) void scatter_k(const int* __restrict__ src, const int* __restrict__ dst,
                                                 int* __restrict__ cursor, int* __restrict__ srcs) {
  int stride = gridDim.x * blockDim.x;
  for (int e = blockIdx.x * blockDim.x + threadIdx.x; e < N_EDGES; e += stride) {
    int p = atomicAdd(&cursor[dst[e]], 1);
    srcs[p] = src[e];
  }
}

// ---------------- weight fragment prep ----------------
// wfrag layout: [o(4)][s(4)][t(8)][lane(64)][i(8)] bf16, o = {W0,rW0,W1,rW1}
__global__ __launch_bounds__(64) void wprep_k(const float* __restrict__ w0, const float* __restrict__ rw0,
                                              const float* __restrict__ w1, const float* __restrict__ rw1,
                                              uint16_t* __restrict__ wfrag) {
  int b = blockIdx.x;  // o*32 + s*8 + t
  int o = b >> 5, s = (b >> 3) & 3, t = b & 7, l = threadIdx.x;
  const float* W = (o == 0) ? w0 : (o == 1) ? rw0 : (o == 2) ? w1 : rw1;
  #pragma unroll
  for (int i = 0; i < 8; ++i) {
    int k = s * 32 + ((l >> 4) << 3) + i;
    int c = t * 16 + (l & 15);
    wfrag[((size_t)b * 64 + l) * 8 + i] = f2bf(W[k * DD + c]);
  }
}

// ---------------- dual GEMM: m = x@W ; r = relu(x@rW + rb) ----------------
template <bool AFFINE>
__global__ __launch_bounds__(256) void gemm_dual(
    const float* __restrict__ xf,        // !AFFINE: fp32 input
    const uint32_t* __restrict__ xb,     // AFFINE: bf16-pair input
    const float2* __restrict__ afin,     // AFFINE: per-col (scale, shift)
    const uint4* __restrict__ wfragL,    // [2][4][8][64] x 16B
    const float* __restrict__ rbias,
    uint16_t* __restrict__ mo, uint16_t* __restrict__ ro) {
  const int w = threadIdx.x >> 6, l = threadIdx.x & 63;
  const int row0 = blockIdx.x * 64 + w * 16;
  const int rload = min(row0 + (l & 15), N_NODES - 1);
  const int kg = (l >> 4) * 8;
  ABFrag a[4];
  #pragma unroll
  for (int s = 0; s < 4; ++s) {
    const int k0 = s * 32 + kg;
    if (!AFFINE) {
      const float4* p = (const float4*)(xf + (size_t)rload * DD + k0);
      float4 x0 = p[0], x1 = p[1];
      a[s].us[0] = f2bf(x0.x); a[s].us[1] = f2bf(x0.y);
      a[s].us[2] = f2bf(x0.z); a[s].us[3] = f2bf(x0.w);
      a[s].us[4] = f2bf(x1.x); a[s].us[5] = f2bf(x1.y);
      a[s].us[6] = f2bf(x1.z); a[s].us[7] = f2bf(x1.w);
    } else {
      uint4 hv = *(const uint4*)(xb + (size_t)rload * 64 + k0 / 2);
      uint32_t hu[4] = {hv.x, hv.y, hv.z, hv.w};
      #pragma unroll
      for (int q = 0; q < 4; ++q) {
        int c = k0 + 2 * q;
        float2 A0 = afin[c], A1 = afin[c + 1];
        float f0 = bf2f((uint16_t)hu[q]) * A0.x + A0.y;
        float f1 = bf2f((uint16_t)(hu[q] >> 16)) * A1.x + A1.y;
        a[s].us[2 * q] = f2bf(f0);
        a[s].us[2 * q + 1] = f2bf(f1);
      }
    }
  }
  const int colb = l & 15;
  const int rbase = row0 + (l >> 4) * 4;
  #pragma unroll
  for (int oo = 0; oo < 2; ++oo) {
    #pragma unroll
    for (int t = 0; t < 8; ++t) {
      f32x4 acc = {0.f, 0.f, 0.f, 0.f};
      #pragma unroll
      for (int s = 0; s < 4; ++s) {
        ABFrag bfr;
        bfr.u4 = wfragL[((oo * 4 + s) * 8 + t) * 64 + l];
        acc = __builtin_amdgcn_mfma_f32_16x16x32_bf16(a[s].v, bfr.v, acc, 0, 0, 0);
      }
      const int col = t * 16 + colb;
      if (oo == 0) {
        #pragma unroll
        for (int rr = 0; rr < 4; ++rr) {
          int rowo = rbase + rr;
          if (rowo < N_NODES) mo[(size_t)rowo * DD + col] = f2bf(acc[rr]);
        }
      } else {
        float rbv = rbias[col];
        #pragma unroll
        for (int rr = 0; rr < 4; ++rr) {
          int rowo = rbase + rr;
          if (rowo < N_NODES) ro[(size_t)rowo * DD + col] = f2bf(fmaxf(acc[rr] + rbv, 0.f));
        }
      }
    }
  }
}

// ---------------- aggregate + bias + relu + residual + BN stats ----------------
__global__ __launch_bounds__(256) void agg_combine(
    const int* __restrict__ row_ptr, const int* __restrict__ srcs,
    const uint32_t* __restrict__ m2, const uint32_t* __restrict__ r2,
    const float* __restrict__ bias, uint32_t* __restrict__ h2,
    float* __restrict__ stats) {
  const int w = threadIdx.x >> 6, l = threadIdx.x & 63;
  const int c0 = 2 * l, c1 = 2 * l + 1;
  const float bb0 = bias[c0], bb1 = bias[c1];
  float ls0 = 0.f, lsq0 = 0.f, ls1 = 0.f, lsq1 = 0.f;
  for (int v = blockIdx.x * 4 + w; v < N_NODES; v += gridDim.x * 4) {
    int j0 = row_ptr[v], j1 = row_ptr[v + 1];
    float a0 = 0.f, a1 = 0.f;
    int j = j0;
    for (; j + 4 <= j1; j += 4) {
      int s0_ = srcs[j], s1_ = srcs[j + 1], s2_ = srcs[j + 2], s3_ = srcs[j + 3];
      uint32_t u0 = m2[(size_t)s0_ * 64 + l];
      uint32_t u1 = m2[(size_t)s1_ * 64 + l];
      uint32_t u2 = m2[(size_t)s2_ * 64 + l];
      uint32_t u3 = m2[(size_t)s3_ * 64 + l];
      a0 += bf2f((uint16_t)u0) + bf2f((uint16_t)u1) + bf2f((uint16_t)u2) + bf2f((uint16_t)u3);
      a1 += bf2f((uint16_t)(u0 >> 16)) + bf2f((uint16_t)(u1 >> 16)) +
            bf2f((uint16_t)(u2 >> 16)) + bf2f((uint16_t)(u3 >> 16));
    }
    for (; j < j1; ++j) {
      uint32_t u = m2[(size_t)srcs[j] * 64 + l];
      a0 += bf2f((uint16_t)u);
      a1 += bf2f((uint16_t)(u >> 16));
    }
    uint32_t rv = r2[(size_t)v * 64 + l];
    float h0v = fmaxf(a0 + bb0, 0.f) + bf2f((uint16_t)rv);
    float h1v = fmaxf(a1 + bb1, 0.f) + bf2f((uint16_t)(rv >> 16));
    h2[(size_t)v * 64 + l] = (uint32_t)f2bf(h0v) | ((uint32_t)f2bf(h1v) << 16);
    ls0 += h0v; lsq0 += h0v * h0v;
    ls1 += h1v; lsq1 += h1v * h1v;
  }
  __shared__ float red[4][128];
  red[w][c0] = ls0; red[w][c1] = ls1;
  __syncthreads();
  if (threadIdx.x < 128) {
    float s = red[0][threadIdx.x] + red[1][threadIdx.x] + red[2][threadIdx.x] + red[3][threadIdx.x];
    atomicAdd(&stats[threadIdx.x], s);
  }
  __syncthreads();
  red[w][c0] = lsq0; red[w][c1] = lsq1;
  __syncthreads();
  if (threadIdx.x < 128) {
    float s = red[0][threadIdx.x] + red[1][threadIdx.x] + red[2][threadIdx.x] + red[3][threadIdx.x];
    atomicAdd(&stats[128 + threadIdx.x], s);
  }
}

// ---------------- BN affine precompute ----------------
__global__ void affine_k(const float* __restrict__ stats, const float* __restrict__ g,
                         const float* __restrict__ beta, float2* __restrict__ af) {
  int c = threadIdx.x;
  float mu = stats[c] / (float)N_NODES;
  float var = stats[128 + c] / (float)N_NODES - mu * mu;
  float sc = g[c] * rsqrtf(var + 1e-5f);
  af[c] = make_float2(sc, beta[c] - mu * sc);
}

// ---------------- final BN apply ----------------
__global__ __launch_bounds__(256) void bn_out(const uint32_t* __restrict__ h2,
                                              const float2* __restrict__ af1,
                                              float* __restrict__ out) {
  int stride = gridDim.x * blockDim.x;
  for (int i = blockIdx.x * blockDim.x + threadIdx.x; i < N_NODES * 64; i += stride) {
    uint32_t u = h2[i];
    int c0 = (i & 63) * 2;
    float2 A = af1[c0], B = af1[c0 + 1];
    float2 o;
    o.x = bf2f((uint16_t)u) * A.x + A.y;
    o.y = bf2f((uint16_t)(u >> 16)) * B.x + B.y;
    *(float2*)(out + (size_t)i * 2) = o;
  }
}

extern "C" void kernel_launch(void* const* d_in, const int* in_sizes, int n_in,
                              void* d_out, int out_size, void* d_ws, size_t ws_size,
                              hipStream_t stream) {
  const float* feats = (const float*)d_in[0];
  const int* srcI = (const int*)d_in[1];
  const int* dstI = (const int*)d_in[2];
  const float* W0 = (const float*)d_in[3];
  const float* b0 = (const float*)d_in[4];
  const float* rW0 = (const float*)d_in[5];
  const float* rb0 = (const float*)d_in[6];
  const float* g0 = (const float*)d_in[7];
  const float* be0 = (const float*)d_in[8];
  const float* W1 = (const float*)d_in[9];
  const float* b1 = (const float*)d_in[10];
  const float* rW1 = (const float*)d_in[11];
  const float* rb1 = (const float*)d_in[12];
  const float* g1 = (const float*)d_in[13];
  const float* be1 = (const float*)d_in[14];
  float* out = (float*)d_out;

  char* ws = (char*)d_ws;
  size_t off = 0;
  auto alloc = [&](size_t bytes) {
    size_t r = off;
    off += (bytes + 255) & ~(size_t)255;
    return r;
  };
  uint16_t* wfrag = (uint16_t*)(ws + alloc(65536 * 2));
  float* stats = (float*)(ws + alloc(512 * 4));
  float2* af = (float2*)(ws + alloc(256 * 8));
  int* row_ptr = (int*)(ws + alloc((N_NODES + 1) * 4));
  int* cursor = (int*)(ws + alloc(N_NODES * 4));
  int* srcs = (int*)(ws + alloc((size_t)N_EDGES * 4));
  uint16_t* mb = (uint16_t*)(ws + alloc((size_t)N_NODES * DD * 2));
  uint16_t* rbuf = (uint16_t*)(ws + alloc((size_t)N_NODES * DD * 2));
  uint16_t* hb = (uint16_t*)(ws + alloc((size_t)N_NODES * DD * 2));

  hipMemsetAsync(cursor, 0, N_NODES * 4, stream);
  hipMemsetAsync(stats, 0, 512 * 4, stream);

  hist_k<<<2048, 256, 0, stream>>>(dstI, cursor);
  scan_k<<<1, 1024, 0, stream>>>(cursor, row_ptr);
  scatter_k<<<2048, 256, 0, stream>>>(srcI, dstI, cursor, srcs);
  wprep_k<<<128, 64, 0, stream>>>(W0, rW0, W1, rW1, wfrag);

  const int gemm_grid = (N_NODES + 63) / 64;
  gemm_dual<false><<<gemm_grid, 256, 0, stream>>>(feats, nullptr, nullptr, (const uint4*)wfrag,
                                                  rb0, mb, rbuf);
  agg_combine<<<2048, 256, 0, stream>>>(row_ptr, srcs, (const uint32_t*)mb, (const uint32_t*)rbuf,
                                        b0, (uint32_t*)hb, stats);
  affine_k<<<1, 128, 0, stream>>>(stats, g0, be0, af);
  gemm_dual<true><<<gemm_grid, 256, 0, stream>>>(nullptr, (const uint32_t*)hb, af,
                                                 (const uint4*)(wfrag + 32768), rb1, mb, rbuf);
  agg_combine<<<2048, 256, 0, stream>>>(row_ptr, srcs, (const uint32_t*)mb, (const uint32_t*)rbuf,
                                        b1, (uint32_t*)hb, stats + 256);
  affine_k<<<1, 128, 0, stream>>>(stats + 256, g1, be1, af + 128);
  bn_out<<<2048, 256, 0, stream>>>((const uint32_t*)hb, af + 128, out);
}